// Round 1
// baseline (183.755 us; speedup 1.0000x reference)
//
#include <hip/hip_runtime.h>
#include <math.h>

#define NUM_CLASSES 10
#define GRID_H 80
#define GRID_W 80
#define NCELLS (GRID_H * GRID_W)
#define NBOX 64
#define SEG (1024 * 1024)   // Hs*Ws per (batch[,channel])

// ws layout (doubles):
//  0..7   obj_sum[b]
//  8..15  box_sum[b]
// 16..23  cls_sum[b]
// 24..31  npos[b]
// 32..39  da_sum[b]
// 40..47  da_cnt[b]
// 48..71  rm_focal[b*3+c]
// 72..95  rm_inter[ch]
// 96..119 rm_probsum[ch]
// 120..143 rm_rtsum[ch]
// 144..167 rm_cnt[ch]
#define WS_DOUBLES 168

__device__ __forceinline__ float bce_logit(float x, float t) {
    // max(x,0) - x*t + log1p(exp(-|x|))
    return fmaxf(x, 0.0f) - x * t + log1pf(expf(-fabsf(x)));
}

__device__ __forceinline__ void reduce_atomic(double v, double* gdst, double* smem) {
    #pragma unroll
    for (int off = 32; off > 0; off >>= 1) v += __shfl_down(v, off, 64);
    int lane = threadIdx.x & 63, wid = threadIdx.x >> 6;
    __syncthreads();               // protect smem reuse across successive calls
    if (lane == 0) smem[wid] = v;
    __syncthreads();
    if (threadIdx.x == 0) {
        double s = 0.0;
        int nw = blockDim.x >> 6;
        for (int i = 0; i < nw; i++) s += smem[i];
        atomicAdd(gdst, s);
    }
}

// ---------------- det (OD) ----------------
__global__ void det_kernel(const float* __restrict__ det_logits,
                           const float* __restrict__ det_yolo,
                           double* __restrict__ acc) {
    __shared__ float gt[NBOX * 5];
    __shared__ double smem[8];
    const int b = blockIdx.y;
    const int tid = threadIdx.x;
    const float* g = det_yolo + (size_t)b * NBOX * 5;
    for (int i = tid; i < NBOX * 5; i += blockDim.x) gt[i] = g[i];
    __syncthreads();

    const int cell = blockIdx.x * 256 + tid;   // 25 * 256 == 6400 exactly

    // last valid box mapping to this cell wins (sequential scatter semantics)
    int win = -1;
    #pragma unroll 4
    for (int n = 0; n < NBOX; n++) {
        const float cf = gt[n * 5 + 0];
        const int cls = (int)cf;
        const bool valid = (cls >= 0) && (cls < NUM_CLASSES) &&
                           (gt[n * 5 + 3] > 0.0f) && (gt[n * 5 + 4] > 0.0f);
        if (valid) {
            const float cx = fminf(fmaxf(gt[n * 5 + 1], 0.0f), 1.0f);
            const float cy = fminf(fmaxf(gt[n * 5 + 2], 0.0f), 1.0f);
            const int gx = min((int)(cx * (float)GRID_W), GRID_W - 1);
            const int gy = min((int)(cy * (float)GRID_H), GRID_H - 1);
            if (gy * GRID_W + gx == cell) win = n;
        }
    }

    const float* dl = det_logits + (size_t)b * 15 * NCELLS;
    const float x_obj = dl[4 * NCELLS + cell];
    const float tobj = (win >= 0) ? 1.0f : 0.0f;
    double obj = (double)bce_logit(x_obj, tobj);
    double boxl = 0.0, clsl = 0.0, posn = 0.0;
    if (win >= 0) {
        posn = 1.0;
        #pragma unroll
        for (int k = 0; k < 4; k++) {
            const float xb = dl[k * NCELLS + cell];
            const float pb = 1.0f / (1.0f + expf(-xb));
            const float tc = fminf(fmaxf(gt[win * 5 + 1 + k], 0.0f), 1.0f);
            const float d = fabsf(pb - tc);
            boxl += (double)((d < 1.0f) ? 0.5f * d * d : d - 0.5f);
        }
        float lx[NUM_CLASSES];
        float mx = -INFINITY;
        #pragma unroll
        for (int c = 0; c < NUM_CLASSES; c++) {
            lx[c] = dl[(5 + c) * NCELLS + cell];
            mx = fmaxf(mx, lx[c]);
        }
        float se = 0.0f;
        #pragma unroll
        for (int c = 0; c < NUM_CLASSES; c++) se += expf(lx[c] - mx);
        const int tcl = (int)gt[win * 5 + 0];
        clsl = -(double)(lx[tcl] - mx - logf(se));
    }
    reduce_atomic(obj,  &acc[0 + b],  smem);
    reduce_atomic(boxl, &acc[8 + b],  smem);
    reduce_atomic(clsl, &acc[16 + b], smem);
    reduce_atomic(posn, &acc[24 + b], smem);
}

// ---------------- DA ----------------
__global__ void da_kernel(const float* __restrict__ logits,
                          const int* __restrict__ mask,
                          double* __restrict__ acc) {
    __shared__ double smem[8];
    const int b = blockIdx.y;
    const float4* lp = (const float4*)(logits + (size_t)b * SEG);
    const int4*   mp = (const int4*)(mask + (size_t)b * SEG);
    const int nvec = SEG / 4;
    double s = 0.0, cnt = 0.0;
    for (int i = blockIdx.x * blockDim.x + threadIdx.x; i < nvec;
         i += gridDim.x * blockDim.x) {
        const float4 x4 = lp[i];
        const int4 m4 = mp[i];
        const float xs[4] = {x4.x, x4.y, x4.z, x4.w};
        const int ms[4] = {m4.x, m4.y, m4.z, m4.w};
        #pragma unroll
        for (int k = 0; k < 4; k++) {
            if (ms[k] != 255) {
                s += (double)bce_logit(xs[k], (float)ms[k]);
                cnt += 1.0;
            }
        }
    }
    reduce_atomic(s,   &acc[32 + b], smem);
    reduce_atomic(cnt, &acc[40 + b], smem);
}

// ---------------- RM ----------------
__global__ void rm_kernel(const float* __restrict__ logits,
                          const int* __restrict__ mask,
                          double* __restrict__ acc) {
    __shared__ double smem[8];
    const int ch = blockIdx.y;   // b*3 + c, 0..23
    const float4* lp = (const float4*)(logits + (size_t)ch * SEG);
    const int4*   mp = (const int4*)(mask + (size_t)ch * SEG);
    const int nvec = SEG / 4;
    double focal = 0.0, inter = 0.0, ps = 0.0, ts = 0.0, cnt = 0.0;
    for (int i = blockIdx.x * blockDim.x + threadIdx.x; i < nvec;
         i += gridDim.x * blockDim.x) {
        const float4 x4 = lp[i];
        const int4 m4 = mp[i];
        const float xs[4] = {x4.x, x4.y, x4.z, x4.w};
        const int ms[4] = {m4.x, m4.y, m4.z, m4.w};
        #pragma unroll
        for (int k = 0; k < 4; k++) {
            if (ms[k] != 255) {
                const float x = xs[k];
                const float t = (float)ms[k];
                const float prob = 1.0f / (1.0f + expf(-x));
                const float rb = bce_logit(x, t);
                const float pt = prob * t + (1.0f - prob) * (1.0f - t);
                const float om = 1.0f - pt;
                focal += (double)(om * om * rb);
                inter += (double)(prob * t);
                ps    += (double)prob;
                ts    += (double)t;
                cnt   += 1.0;
            }
        }
    }
    reduce_atomic(focal, &acc[48 + ch],  smem);
    reduce_atomic(inter, &acc[72 + ch],  smem);
    reduce_atomic(ps,    &acc[96 + ch],  smem);
    reduce_atomic(ts,    &acc[120 + ch], smem);
    reduce_atomic(cnt,   &acc[144 + ch], smem);
}

// ---------------- finalize ----------------
__global__ void final_kernel(const double* __restrict__ acc,
                             const int* __restrict__ has_det,
                             const int* __restrict__ has_da,
                             const int* __restrict__ has_rm,
                             float* __restrict__ out, int B) {
    if (threadIdx.x != 0 || blockIdx.x != 0) return;
    double od_num = 0.0, wsum = 0.0;
    for (int b = 0; b < B; b++) {
        const double np_ = fmax(acc[24 + b], 1.0);
        const double obj_b = acc[0 + b] / (double)NCELLS;
        const double box_b = acc[8 + b] / (np_ * 4.0);
        const double cls_b = acc[16 + b] / np_;
        const double w = (double)has_det[b];
        od_num += (obj_b + box_b + cls_b) * w;
        wsum += w;
    }
    const double od = od_num / fmax(wsum, 1.0);

    double da_num = 0.0, daw = 0.0;
    for (int b = 0; b < B; b++) {
        const double c = acc[40 + b];
        const double da_b = acc[32 + b] / fmax(c, 1.0);
        const double w = (double)has_da[b] * (c > 0.0 ? 1.0 : 0.0);
        da_num += da_b * w;
        daw += w;
    }
    const double da = da_num / fmax(daw, 1.0);

    double rm_num = 0.0, rmw = 0.0;
    for (int ch = 0; ch < 3 * B; ch++) {
        const double c = acc[144 + ch];
        const double focal = acc[48 + ch] / fmax(c, 1.0);
        const double dice = 1.0 - (2.0 * acc[72 + ch] + 1e-6) /
                                  (acc[96 + ch] + acc[120 + ch] + 1e-6);
        const double w = (double)has_rm[ch] * (c > 0.0 ? 1.0 : 0.0);
        rm_num += (focal + dice) * w;
        rmw += w;
    }
    const double rm = rm_num / fmax(rmw, 1.0);

    const double total = od + da + 2.0 * rm;
    out[0] = (float)total;
    out[1] = (float)od;
    out[2] = (float)da;
    out[3] = (float)rm;
}

extern "C" void kernel_launch(void* const* d_in, const int* in_sizes, int n_in,
                              void* d_out, int out_size, void* d_ws, size_t ws_size,
                              hipStream_t stream) {
    const float* det_logits = (const float*)d_in[0];
    const float* det_yolo   = (const float*)d_in[1];
    const float* da_logits  = (const float*)d_in[2];
    const int*   da_mask    = (const int*)d_in[3];
    const float* rm_logits  = (const float*)d_in[4];
    const int*   rm_mask    = (const int*)d_in[5];
    const int*   has_det    = (const int*)d_in[6];
    const int*   has_da     = (const int*)d_in[7];
    const int*   has_rm     = (const int*)d_in[8];
    float* out = (float*)d_out;
    double* acc = (double*)d_ws;

    const int B = in_sizes[6];   // 8

    hipMemsetAsync(acc, 0, WS_DOUBLES * sizeof(double), stream);

    det_kernel<<<dim3(NCELLS / 256, B), 256, 0, stream>>>(det_logits, det_yolo, acc);
    da_kernel<<<dim3(256, B), 256, 0, stream>>>(da_logits, da_mask, acc);
    rm_kernel<<<dim3(128, 3 * B), 256, 0, stream>>>(rm_logits, rm_mask, acc);
    final_kernel<<<1, 64, 0, stream>>>(acc, has_det, has_da, has_rm, out, B);
}

// Round 2
// 112.861 us; speedup vs baseline: 1.6282x; 1.6282x over previous
//
#include <hip/hip_runtime.h>
#include <math.h>

#define NUM_CLASSES 10
#define GRID_H 80
#define GRID_W 80
#define NCELLS (GRID_H * GRID_W)
#define NBOX 64
#define SEG (1024 * 1024)   // Hs*Ws per (batch[,channel])

// ws layout (doubles):
//  0..7    obj_sum[b]
//  8..15   box_sum[b]
// 16..23   cls_sum[b]
// 24..31   npos[b]
// 32..39   da_sum[b]
// 40..47   da_cnt[b]
// 48..71   rm_focal[b*3+c]
// 72..95   rm_inter[ch]
// 96..119  rm_probsum[ch]
// 120..143 rm_rtsum[ch]
// 144..167 rm_cnt[ch]
#define WS_DOUBLES 168

__device__ __forceinline__ void reduce_atomic(double v, double* gdst, double* smem) {
    #pragma unroll
    for (int off = 32; off > 0; off >>= 1) v += __shfl_down(v, off, 64);
    int lane = threadIdx.x & 63, wid = threadIdx.x >> 6;
    __syncthreads();               // protect smem reuse across successive calls
    if (lane == 0) smem[wid] = v;
    __syncthreads();
    if (threadIdx.x == 0) {
        double s = 0.0;
        int nw = blockDim.x >> 6;
        for (int i = 0; i < nw; i++) s += smem[i];
        atomicAdd(gdst, s);
    }
}

// numerically stable bce via -log(pt); sp = sigmoid(|x|), sn = sigmoid(-|x|)
// prob = sigmoid(x); pt = prob*t + (1-prob)*(1-t); 1-pt is the opposite select.
__device__ __forceinline__ float bce_logit_stable(float x, float t) {
    const float e  = __expf(-fabsf(x));
    const float sp = __builtin_amdgcn_rcpf(1.0f + e);
    const float sn = e * sp;
    const bool xp = (x >= 0.0f);
    const bool tp = (t > 0.5f);
    const float pt = (xp == tp) ? sp : sn;
    return -__logf(pt);
}

// ---------------- det (OD) ----------------
__global__ void det_kernel(const float* __restrict__ det_logits,
                           const float* __restrict__ det_yolo,
                           double* __restrict__ acc) {
    __shared__ float gt[NBOX * 5];
    __shared__ double smem[8];
    const int b = blockIdx.y;
    const int tid = threadIdx.x;
    const float* g = det_yolo + (size_t)b * NBOX * 5;
    for (int i = tid; i < NBOX * 5; i += blockDim.x) gt[i] = g[i];
    __syncthreads();

    const int cell = blockIdx.x * 256 + tid;   // 25 * 256 == 6400 exactly

    // last valid box mapping to this cell wins (sequential scatter semantics)
    int win = -1;
    #pragma unroll 4
    for (int n = 0; n < NBOX; n++) {
        const float cf = gt[n * 5 + 0];
        const int cls = (int)cf;
        const bool valid = (cls >= 0) && (cls < NUM_CLASSES) &&
                           (gt[n * 5 + 3] > 0.0f) && (gt[n * 5 + 4] > 0.0f);
        if (valid) {
            const float cx = fminf(fmaxf(gt[n * 5 + 1], 0.0f), 1.0f);
            const float cy = fminf(fmaxf(gt[n * 5 + 2], 0.0f), 1.0f);
            const int gx = min((int)(cx * (float)GRID_W), GRID_W - 1);
            const int gy = min((int)(cy * (float)GRID_H), GRID_H - 1);
            if (gy * GRID_W + gx == cell) win = n;
        }
    }

    const float* dl = det_logits + (size_t)b * 15 * NCELLS;
    const float x_obj = dl[4 * NCELLS + cell];
    const float tobj = (win >= 0) ? 1.0f : 0.0f;
    double obj = (double)bce_logit_stable(x_obj, tobj);
    double boxl = 0.0, clsl = 0.0, posn = 0.0;
    if (win >= 0) {
        posn = 1.0;
        #pragma unroll
        for (int k = 0; k < 4; k++) {
            const float xb = dl[k * NCELLS + cell];
            const float e = __expf(-fabsf(xb));
            const float sp = __builtin_amdgcn_rcpf(1.0f + e);
            const float pb = (xb >= 0.0f) ? sp : e * sp;   // sigmoid(xb)
            const float tc = fminf(fmaxf(gt[win * 5 + 1 + k], 0.0f), 1.0f);
            const float d = fabsf(pb - tc);
            boxl += (double)((d < 1.0f) ? 0.5f * d * d : d - 0.5f);
        }
        float lx[NUM_CLASSES];
        float mx = -INFINITY;
        #pragma unroll
        for (int c = 0; c < NUM_CLASSES; c++) {
            lx[c] = dl[(5 + c) * NCELLS + cell];
            mx = fmaxf(mx, lx[c]);
        }
        float se = 0.0f;
        #pragma unroll
        for (int c = 0; c < NUM_CLASSES; c++) se += __expf(lx[c] - mx);
        const int tcl = (int)gt[win * 5 + 0];
        clsl = -(double)(lx[tcl] - mx - __logf(se));
    }
    reduce_atomic(obj,  &acc[0 + b],  smem);
    reduce_atomic(boxl, &acc[8 + b],  smem);
    reduce_atomic(clsl, &acc[16 + b], smem);
    reduce_atomic(posn, &acc[24 + b], smem);
}

// ---------------- DA ----------------
__global__ void da_kernel(const float* __restrict__ logits,
                          const int* __restrict__ mask,
                          double* __restrict__ acc) {
    __shared__ double smem[8];
    const int b = blockIdx.y;
    const float4* lp = (const float4*)(logits + (size_t)b * SEG);
    const int4*   mp = (const int4*)(mask + (size_t)b * SEG);
    const int nvec = SEG / 4;
    float s = 0.0f, cnt = 0.0f;
    for (int i = blockIdx.x * blockDim.x + threadIdx.x; i < nvec;
         i += gridDim.x * blockDim.x) {
        const float4 x4 = lp[i];
        const int4 m4 = mp[i];
        const float xs[4] = {x4.x, x4.y, x4.z, x4.w};
        const int ms[4] = {m4.x, m4.y, m4.z, m4.w};
        #pragma unroll
        for (int k = 0; k < 4; k++) {
            const float x = xs[k];
            const int m = ms[k];
            const float vf = (m != 255) ? 1.0f : 0.0f;
            const float t = (m != 255) ? (float)m : 0.0f;
            const float e  = __expf(-fabsf(x));
            const float sp = __builtin_amdgcn_rcpf(1.0f + e);
            const float sn = e * sp;
            const bool xp = (x >= 0.0f);
            const bool tp = (t > 0.5f);
            const float pt = (xp == tp) ? sp : sn;
            s += vf * (-__logf(pt));
            cnt += vf;
        }
    }
    reduce_atomic((double)s,   &acc[32 + b], smem);
    reduce_atomic((double)cnt, &acc[40 + b], smem);
}

// ---------------- RM ----------------
__global__ void rm_kernel(const float* __restrict__ logits,
                          const int* __restrict__ mask,
                          double* __restrict__ acc) {
    __shared__ double smem[8];
    const int ch = blockIdx.y;   // b*3 + c, 0..23
    const float4* lp = (const float4*)(logits + (size_t)ch * SEG);
    const int4*   mp = (const int4*)(mask + (size_t)ch * SEG);
    const int nvec = SEG / 4;
    float focal = 0.0f, inter = 0.0f, ps = 0.0f, ts = 0.0f, cnt = 0.0f;
    for (int i = blockIdx.x * blockDim.x + threadIdx.x; i < nvec;
         i += gridDim.x * blockDim.x) {
        const float4 x4 = lp[i];
        const int4 m4 = mp[i];
        const float xs[4] = {x4.x, x4.y, x4.z, x4.w};
        const int ms[4] = {m4.x, m4.y, m4.z, m4.w};
        #pragma unroll
        for (int k = 0; k < 4; k++) {
            const float x = xs[k];
            const int m = ms[k];
            const float vf = (m != 255) ? 1.0f : 0.0f;
            const float t = (m != 255) ? (float)m : 0.0f;
            const float e  = __expf(-fabsf(x));
            const float sp = __builtin_amdgcn_rcpf(1.0f + e);
            const float sn = e * sp;
            const bool xp = (x >= 0.0f);
            const bool tp = (t > 0.5f);
            const float prob = xp ? sp : sn;          // sigmoid(x)
            const float pt = (xp == tp) ? sp : sn;    // prob*t + (1-prob)*(1-t)
            const float om = (xp == tp) ? sn : sp;    // 1 - pt (stable)
            const float bce = -__logf(pt);
            focal += vf * (om * om * bce);
            inter += vf * (prob * t);
            ps    += vf * prob;
            ts    += t;
            cnt   += vf;
        }
    }
    reduce_atomic((double)focal, &acc[48 + ch],  smem);
    reduce_atomic((double)inter, &acc[72 + ch],  smem);
    reduce_atomic((double)ps,    &acc[96 + ch],  smem);
    reduce_atomic((double)ts,    &acc[120 + ch], smem);
    reduce_atomic((double)cnt,   &acc[144 + ch], smem);
}

// ---------------- finalize ----------------
__global__ void final_kernel(const double* __restrict__ acc,
                             const int* __restrict__ has_det,
                             const int* __restrict__ has_da,
                             const int* __restrict__ has_rm,
                             float* __restrict__ out, int B) {
    if (threadIdx.x != 0 || blockIdx.x != 0) return;
    double od_num = 0.0, wsum = 0.0;
    for (int b = 0; b < B; b++) {
        const double np_ = fmax(acc[24 + b], 1.0);
        const double obj_b = acc[0 + b] / (double)NCELLS;
        const double box_b = acc[8 + b] / (np_ * 4.0);
        const double cls_b = acc[16 + b] / np_;
        const double w = (double)has_det[b];
        od_num += (obj_b + box_b + cls_b) * w;
        wsum += w;
    }
    const double od = od_num / fmax(wsum, 1.0);

    double da_num = 0.0, daw = 0.0;
    for (int b = 0; b < B; b++) {
        const double c = acc[40 + b];
        const double da_b = acc[32 + b] / fmax(c, 1.0);
        const double w = (double)has_da[b] * (c > 0.0 ? 1.0 : 0.0);
        da_num += da_b * w;
        daw += w;
    }
    const double da = da_num / fmax(daw, 1.0);

    double rm_num = 0.0, rmw = 0.0;
    for (int ch = 0; ch < 3 * B; ch++) {
        const double c = acc[144 + ch];
        const double focal = acc[48 + ch] / fmax(c, 1.0);
        const double dice = 1.0 - (2.0 * acc[72 + ch] + 1e-6) /
                                  (acc[96 + ch] + acc[120 + ch] + 1e-6);
        const double w = (double)has_rm[ch] * (c > 0.0 ? 1.0 : 0.0);
        rm_num += (focal + dice) * w;
        rmw += w;
    }
    const double rm = rm_num / fmax(rmw, 1.0);

    const double total = od + da + 2.0 * rm;
    out[0] = (float)total;
    out[1] = (float)od;
    out[2] = (float)da;
    out[3] = (float)rm;
}

extern "C" void kernel_launch(void* const* d_in, const int* in_sizes, int n_in,
                              void* d_out, int out_size, void* d_ws, size_t ws_size,
                              hipStream_t stream) {
    const float* det_logits = (const float*)d_in[0];
    const float* det_yolo   = (const float*)d_in[1];
    const float* da_logits  = (const float*)d_in[2];
    const int*   da_mask    = (const int*)d_in[3];
    const float* rm_logits  = (const float*)d_in[4];
    const int*   rm_mask    = (const int*)d_in[5];
    const int*   has_det    = (const int*)d_in[6];
    const int*   has_da     = (const int*)d_in[7];
    const int*   has_rm     = (const int*)d_in[8];
    float* out = (float*)d_out;
    double* acc = (double*)d_ws;

    const int B = in_sizes[6];   // 8

    hipMemsetAsync(acc, 0, WS_DOUBLES * sizeof(double), stream);

    det_kernel<<<dim3(NCELLS / 256, B), 256, 0, stream>>>(det_logits, det_yolo, acc);
    da_kernel<<<dim3(128, B), 256, 0, stream>>>(da_logits, da_mask, acc);
    rm_kernel<<<dim3(128, 3 * B), 256, 0, stream>>>(rm_logits, rm_mask, acc);
    final_kernel<<<1, 64, 0, stream>>>(acc, has_det, has_da, has_rm, out, B);
}